// Round 3
// baseline (743.303 us; speedup 1.0000x reference)
//
#include <hip/hip_runtime.h>

#define NCAT 32
#define NTOK 512
#define HID  512
#define EMB  1024
#define DSTATE 192
#define CHUNK 16

// ws layout:
//   [0,128)        int cnt[32]
//   [128,136)      int nW[1]        (chunks of 16 tokens; max sum ceil(n/16) = 63)
//   [256,512)      int work[64]     entries: cat | (chunk<<8)
//   [1024,66560)   int toklist[32][512]
//   [66560,+4MiB)  float H[512 tok][4 mod][512]

__global__ __launch_bounds__(512) void bucket_kernel(
    const int* __restrict__ ids, int* __restrict__ cnt, int* __restrict__ nW,
    int* __restrict__ work, int* __restrict__ toklist)
{
    __shared__ int scnt[NCAT];
    const int tid = threadIdx.x;
    if (tid < NCAT) scnt[tid] = 0;
    __syncthreads();
    const int c = ids[tid];                       // 512 threads == 512 tokens
    const int pos = atomicAdd(&scnt[c], 1);       // LDS atomic: cheap
    toklist[c * NTOK + pos] = tid;
    __syncthreads();
    if (tid == 0) {
        int n1 = 0;
        for (int cc = 0; cc < NCAT; ++cc) {
            const int n = scnt[cc];
            cnt[cc] = n;
            for (int ch = 0; ch * CHUNK < n; ++ch) work[n1++] = cc | (ch << 8);
        }
        nW[0] = n1;
    }
}

// K-loop with explicit ping-pong register prefetch.
// NG groups of 8 K-rows (K = 8*NG, NG even, >= 4). WS = row stride (floats).
// Thread owns 2 cols; acc[16] tokens. sV is [16][2*NG] float4 (zero-padded).
template <int NG, int WS>
__device__ __forceinline__ void mlp_kloop(
    const float* __restrict__ Wcol, const float4* __restrict__ sV,
    float2* __restrict__ acc)
{
    float2 wa[8], wb[8];

    auto LOADW = [&](float2* w, int g) {
        const float* p = Wcol + (size_t)g * 8 * WS;
#pragma unroll
        for (int r = 0; r < 8; ++r) w[r] = *(const float2*)(p + r * WS);
    };
    auto FMAG = [&](const float2* w, int g) {
#pragma unroll
        for (int k4 = 0; k4 < 2; ++k4) {
#pragma unroll
            for (int t = 0; t < 16; ++t) {
                const float4 v = sV[t * (2 * NG) + g * 2 + k4];
                acc[t].x += v.x * w[4*k4+0].x + v.y * w[4*k4+1].x
                          + v.z * w[4*k4+2].x + v.w * w[4*k4+3].x;
                acc[t].y += v.x * w[4*k4+0].y + v.y * w[4*k4+1].y
                          + v.z * w[4*k4+2].y + v.w * w[4*k4+3].y;
            }
        }
    };

    LOADW(wa, 0);
    LOADW(wb, 1);
#pragma unroll 1
    for (int g = 0; g < NG - 4; g += 2) {
        FMAG(wa, g);     LOADW(wa, g + 2);
        FMAG(wb, g + 1); LOADW(wb, g + 3);
    }
    FMAG(wa, NG - 4); LOADW(wa, NG - 2);
    FMAG(wb, NG - 3); LOADW(wb, NG - 1);
    FMAG(wa, NG - 2);
    FMAG(wb, NG - 1);
}

// grid (64 slots, 4 mod, 2 colhalf), 128 threads. 16 tokens/block zero-padded,
// thread owns 2 hid cols (z*256 + 2*tid).
__global__ __launch_bounds__(128, 2) void layer1_kernel(
    const float* __restrict__ state,
    const int* __restrict__ cnt, const int* __restrict__ toklist,
    const int* __restrict__ nW, const int* __restrict__ work,
    const float* __restrict__ W1_0, const float* __restrict__ W1_1,
    const float* __restrict__ W1_2, const float* __restrict__ W1_3,
    const float* __restrict__ b1_0, const float* __restrict__ b1_1,
    const float* __restrict__ b1_2, const float* __restrict__ b1_3,
    float* __restrict__ H)
{
    const int slot = blockIdx.x, mod = blockIdx.y;
    if (slot >= nW[0]) return;
    const int ent = work[slot];
    const int cat = ent & 255, chunk = ent >> 8;
    const int nC = cnt[cat];
    const int start = chunk * CHUNK;
    int nThis = nC - start;
    if (nThis > CHUNK) nThis = CHUNK;
    const int tid = threadIdx.x;
    const int col = blockIdx.z * 256 + 2 * tid;

    const int L   = (mod < 2) ? 64 : 32;
    const int lsh = (mod < 2) ? 4 : 3;             // log2(L/4)
    const int lf4 = 1 << lsh;
    const int off = (mod == 0) ? 0 : (mod == 1) ? 64 : (mod == 2) ? 128 : 160;

    __shared__ float4 sX[16 * 16];                 // up to 16 tok x 16 f4 (4 KiB)
    __shared__ int sTok[16];
    if (tid < 16) sTok[tid] = (tid < nThis) ? toklist[cat * NTOK + start + tid] : 0;
    __syncthreads();

    for (int idx = tid; idx < (16 << lsh); idx += 128) {
        const int t = idx >> lsh, e = idx & (lf4 - 1);
        float4 v = make_float4(0.f, 0.f, 0.f, 0.f);
        if (t < nThis)
            v = ((const float4*)(state + sTok[t] * DSTATE + off))[e];
        sX[t * lf4 + e] = v;
    }
    __syncthreads();

    const float* W1 = (mod == 0) ? W1_0 : (mod == 1) ? W1_1 : (mod == 2) ? W1_2 : W1_3;
    const float* b1 = (mod == 0) ? b1_0 : (mod == 1) ? b1_1 : (mod == 2) ? b1_2 : b1_3;
    const float* Wcol = W1 + (size_t)cat * L * HID + col;

    float2 acc[16];
#pragma unroll
    for (int t = 0; t < 16; ++t) acc[t] = make_float2(0.f, 0.f);

    // sX stride is lf4 = 2*NG floats4: NG=8 for L=64, NG=4 for L=32
    if (mod < 2) mlp_kloop<8, HID>(Wcol, sX, acc);
    else         mlp_kloop<4, HID>(Wcol, sX, acc);

    const float2 b = *(const float2*)(b1 + cat * HID + col);
#pragma unroll
    for (int t = 0; t < 16; ++t) {
        if (t >= nThis) break;
        float2 h;
        h.x = acc[t].x + b.x; h.x = h.x > 0.f ? h.x : 0.f;
        h.y = acc[t].y + b.y; h.y = h.y > 0.f ? h.y : 0.f;
        *(float2*)(H + (size_t)(sTok[t] * 4 + mod) * HID + col) = h;
    }
}

// grid (64 slots, 4 mod, 4 colquarter), 128 threads. 16 tokens/block zero-padded,
// thread owns 2 emb cols (z*256 + 2*tid). Ping-pong prefetch keeps ~16 weight
// loads in flight per wave (the round-2 version drained vmcnt every 4 loads).
__global__ __launch_bounds__(128, 2) void layer2_kernel(
    const int* __restrict__ cnt, const int* __restrict__ toklist,
    const int* __restrict__ nW, const int* __restrict__ work,
    const float* __restrict__ H,
    const float* __restrict__ W2_0, const float* __restrict__ W2_1,
    const float* __restrict__ W2_2, const float* __restrict__ W2_3,
    const float* __restrict__ b2_0, const float* __restrict__ b2_1,
    const float* __restrict__ b2_2, const float* __restrict__ b2_3,
    const float* __restrict__ te_0, const float* __restrict__ te_1,
    const float* __restrict__ te_2, const float* __restrict__ te_3,
    float* __restrict__ out)
{
    const int slot = blockIdx.x, mod = blockIdx.y;
    if (slot >= nW[0]) return;
    const int ent = work[slot];
    const int cat = ent & 255, chunk = ent >> 8;
    const int nC = cnt[cat];
    const int start = chunk * CHUNK;
    int nThis = nC - start;
    if (nThis > CHUNK) nThis = CHUNK;
    const int tid = threadIdx.x;
    const int col = blockIdx.z * 256 + 2 * tid;

    __shared__ float4 sH[16 * 128];                // 32 KiB, [t][k4] zero-padded
    __shared__ int sTok[16];
    if (tid < 16) sTok[tid] = (tid < nThis) ? toklist[cat * NTOK + start + tid] : 0;
    __syncthreads();

    for (int idx = tid; idx < 16 * 128; idx += 128) {   // 16 f4 per thread
        const int t = idx >> 7, e4 = idx & 127;
        float4 v = make_float4(0.f, 0.f, 0.f, 0.f);
        if (t < nThis)
            v = ((const float4*)(H + (size_t)(sTok[t] * 4 + mod) * HID))[e4];
        sH[idx] = v;
    }
    __syncthreads();

    const float* W2 = (mod == 0) ? W2_0 : (mod == 1) ? W2_1 : (mod == 2) ? W2_2 : W2_3;
    const float* b2 = (mod == 0) ? b2_0 : (mod == 1) ? b2_1 : (mod == 2) ? b2_2 : b2_3;
    const float* te = (mod == 0) ? te_0 : (mod == 1) ? te_1 : (mod == 2) ? te_2 : te_3;

    const float* Wcol = W2 + (size_t)cat * HID * EMB + col;

    float2 acc[16];
#pragma unroll
    for (int t = 0; t < 16; ++t) acc[t] = make_float2(0.f, 0.f);

    mlp_kloop<64, EMB>(Wcol, sH, acc);             // K = 512

    const float2 bb = *(const float2*)(b2 + cat * EMB + col);
    const float2 tt = *(const float2*)(te + col);
    const float2 b2v = make_float2(bb.x + tt.x, bb.y + tt.y);
#pragma unroll
    for (int t = 0; t < 16; ++t) {
        if (t >= nThis) break;
        *(float2*)(out + (size_t)(sTok[t] * 4 + mod) * EMB + col) =
            make_float2(acc[t].x + b2v.x, acc[t].y + b2v.y);
    }
}

extern "C" void kernel_launch(void* const* d_in, const int* in_sizes, int n_in,
                              void* d_out, int out_size, void* d_ws, size_t ws_size,
                              hipStream_t stream) {
    const float* state = (const float*)d_in[0];
    const int*   ids   = (const int*)d_in[1];
    const float *W1[4], *b1[4], *W2[4], *b2[4], *te[4];
    for (int m = 0; m < 4; ++m) {
        W1[m] = (const float*)d_in[2 + 5 * m + 0];
        b1[m] = (const float*)d_in[2 + 5 * m + 1];
        W2[m] = (const float*)d_in[2 + 5 * m + 2];
        b2[m] = (const float*)d_in[2 + 5 * m + 3];
        te[m] = (const float*)d_in[2 + 5 * m + 4];
    }
    char* ws = (char*)d_ws;
    int*   cnt     = (int*)ws;
    int*   nW      = (int*)(ws + 128);
    int*   work    = (int*)(ws + 256);
    int*   toklist = (int*)(ws + 1024);
    float* H       = (float*)(ws + 66560);
    float* out     = (float*)d_out;

    bucket_kernel<<<1, 512, 0, stream>>>(ids, cnt, nW, work, toklist);
    layer1_kernel<<<dim3(64, 4, 2), 128, 0, stream>>>(
        state, cnt, toklist, nW, work,
        W1[0], W1[1], W1[2], W1[3],
        b1[0], b1[1], b1[2], b1[3], H);
    layer2_kernel<<<dim3(64, 4, 4), 128, 0, stream>>>(
        cnt, toklist, nW, work, H,
        W2[0], W2[1], W2[2], W2[3],
        b2[0], b2[1], b2[2], b2[3],
        te[0], te[1], te[2], te[3], out);
}